// Round 1
// baseline (364.856 us; speedup 1.0000x reference)
//
#include <hip/hip_runtime.h>
#include <stdint.h>

#define N_PTS 131072
#define NC 256
#define NSEG 16
#define BN_EPSF 1e-5f

typedef __attribute__((ext_vector_type(8))) short bf16x8;
typedef __attribute__((ext_vector_type(4))) float f32x4;

__device__ __forceinline__ unsigned short f2bf(float f) {
  union { float f; uint32_t u; } v; v.f = f;
  uint32_t u = v.u;
  uint32_t r = (u + 0x7fffu + ((u >> 16) & 1u)) >> 16;
  return (unsigned short)r;
}

// Chunk swizzle: within each 64-col (128B) window of a row, XOR the 8-col
// (16B) chunk index with (row&7). Writers store pre-swizzled; global_load_lds
// copies verbatim (linear dest); ds_read_b128 applies the same XOR -> 2-way
// bank aliasing (free) instead of 8-way, staging stays line-coalesced.
__device__ __forceinline__ int swz(int col, int row) {
  return (col & ~63) | ((((col >> 3) & 7) ^ (row & 7)) << 3) | (col & 7);
}

__device__ __forceinline__ void gll16(const unsigned short* g, unsigned short* l) {
  __builtin_amdgcn_global_load_lds(
      (const __attribute__((address_space(1))) void*)g,
      (__attribute__((address_space(3))) void*)l, 16, 0, 0);
}

// ---- prep: blocks 0..15 transpose+convert+swizzle W1_top; 16..33 zero stats ----
__global__ __launch_bounds__(256) void k_prep(const float* __restrict__ W1,
                                              unsigned short* __restrict__ w1t,
                                              float* __restrict__ zerobuf) {
  int b = blockIdx.x, t = threadIdx.x;
  if (b >= 16) {
    int i = (b - 16) * 256 + t;
    if (i < 4608) zerobuf[i] = 0.f;
    return;
  }
  __shared__ float tile[64][65];
  int bx = b & 3, by = b >> 2;
  int k0 = by * 64, j0 = bx * 64;
  int r = t >> 6, c = t & 63;
#pragma unroll
  for (int i = 0; i < 16; ++i) {
    int kk = r + i * 4;
    tile[kk][c] = W1[(size_t)(k0 + kk) * NC + j0 + c];
  }
  __syncthreads();
#pragma unroll
  for (int i = 0; i < 16; ++i) {
    int jj = r + i * 4;
    int row = j0 + jj, col = k0 + c;
    w1t[(size_t)row * NC + swz(col, row)] = f2bf(tile[c][jj]);
  }
}

// ---- pass 1: x fp32 -> x_bf (swizzled), per-segment column sums ----
__global__ __launch_bounds__(256) void k_segsum_convert(
    const float* __restrict__ x, const int* __restrict__ o,
    unsigned short* __restrict__ x_bf, float* __restrict__ seg_sums) {
  __shared__ int o_s[NSEG];
  __shared__ float s_acc[2][NC];
  int t = threadIdx.x;
  if (t < NSEG) o_s[t] = o[t];
  s_acc[0][t] = 0.f;
  s_acc[1][t] = 0.f;
  __syncthreads();
  int g = t >> 6, l = t & 63;
  int row0 = blockIdx.x * 64;
  int c0 = l * 4;
  int s0 = 0;
  while (o_s[s0] <= row0) ++s0;
  int e0 = o_s[s0];
  int s1 = (s0 < NSEG - 1) ? s0 + 1 : s0;
  float4 accA = {0.f, 0.f, 0.f, 0.f}, accB = {0.f, 0.f, 0.f, 0.f};
  const float4* xv = (const float4*)x;
#pragma unroll
  for (int i = 0; i < 16; ++i) {
    int r = row0 + g + i * 4;
    float4 v = xv[(size_t)r * 64 + l];
    ushort4 b;
    b.x = f2bf(v.x); b.y = f2bf(v.y); b.z = f2bf(v.z); b.w = f2bf(v.w);
    *(ushort4*)(x_bf + (size_t)r * NC + swz(c0, r)) = b;
    bool inA = (r < e0);
    accA.x += inA ? v.x : 0.f; accB.x += inA ? 0.f : v.x;
    accA.y += inA ? v.y : 0.f; accB.y += inA ? 0.f : v.y;
    accA.z += inA ? v.z : 0.f; accB.z += inA ? 0.f : v.z;
    accA.w += inA ? v.w : 0.f; accB.w += inA ? 0.f : v.w;
  }
  atomicAdd(&s_acc[0][c0 + 0], accA.x);
  atomicAdd(&s_acc[0][c0 + 1], accA.y);
  atomicAdd(&s_acc[0][c0 + 2], accA.z);
  atomicAdd(&s_acc[0][c0 + 3], accA.w);
  atomicAdd(&s_acc[1][c0 + 0], accB.x);
  atomicAdd(&s_acc[1][c0 + 1], accB.y);
  atomicAdd(&s_acc[1][c0 + 2], accB.z);
  atomicAdd(&s_acc[1][c0 + 3], accB.w);
  __syncthreads();
  atomicAdd(&seg_sums[s0 * NC + t], s_acc[0][t]);
  atomicAdd(&seg_sums[s1 * NC + t], s_acc[1][t]);
}

// ---- tiny per-segment MLP: means -> y=relu(means@W2+b2) -> z=y@W1_bot+b1 ----
__global__ __launch_bounds__(256) void k_seg_mlp(
    const int* __restrict__ o, const float* __restrict__ seg_sums,
    const float* __restrict__ W1, const float* __restrict__ b1,
    const float* __restrict__ W2, const float* __restrict__ b2,
    float* __restrict__ z) {
  __shared__ float mean_s[NC];
  __shared__ float y_s[NC];
  int b = blockIdx.x, j = threadIdx.x;
  int start = (b == 0) ? 0 : o[b - 1];
  float inv = 1.f / (float)(o[b] - start);
  mean_s[j] = seg_sums[b * NC + j] * inv;
  __syncthreads();
  float a = b2[j];
  for (int k = 0; k < NC; ++k) a += mean_s[k] * W2[k * NC + j];
  y_s[j] = fmaxf(a, 0.f);
  __syncthreads();
  float a2 = b1[j];
  for (int k = 0; k < NC; ++k) a2 += y_s[k] * W1[(NC + k) * NC + j];
  z[b * NC + j] = a2;
}

// ---- GEMM #1: h = x_bf@W1_top + z[seg] in registers; emit BN col stats only ----
// 2048 blocks x 64 rows x 256 cols; 4 waves, wave w owns cols [w*64, w*64+64)
__global__ __launch_bounds__(256) void k_gemm_stats(
    const unsigned short* __restrict__ x_bf, const unsigned short* __restrict__ w1t,
    const int* __restrict__ o, const float* __restrict__ z,
    float* __restrict__ colsum, float* __restrict__ colsumsq) {
  __shared__ __align__(16) unsigned short lA[64 * 64];   // [row][64k], swizzled chunks
  __shared__ __align__(16) unsigned short lB[256 * 64];
  __shared__ float s_sum[NC], s_sq[NC];
  __shared__ int o_s[NSEG];
  int t = threadIdx.x, lane = t & 63, w = t >> 6;
  int row0 = blockIdx.x * 64;
  if (t < NSEG) o_s[t] = o[t];

  f32x4 acc[4][4] = {};
  for (int kt = 0; kt < 4; ++kt) {
    // stage A (8 KiB): 2 issues; stage B (32 KiB): 8 issues — verbatim copies
    gll16(x_bf + (size_t)(row0 + (t >> 3)) * NC + kt * 64 + (t & 7) * 8, lA + t * 8);
    gll16(x_bf + (size_t)(row0 + (t >> 3) + 32) * NC + kt * 64 + (t & 7) * 8,
          lA + (t + 256) * 8);
#pragma unroll
    for (int i = 0; i < 8; ++i) {
      int tp = t + i * 256;
      gll16(w1t + (size_t)(tp >> 3) * NC + kt * 64 + (t & 7) * 8, lB + tp * 8);
    }
    __syncthreads();
#pragma unroll
    for (int kk = 0; kk < 2; ++kk) {
      bf16x8 af[4], bfr[4];
      int sl = kk * 4 + (lane >> 4);
#pragma unroll
      for (int mm = 0; mm < 4; ++mm) {
        int r = mm * 16 + (lane & 15);
        af[mm] = *(const bf16x8*)(lA + r * 64 + ((sl ^ (r & 7)) << 3));
      }
#pragma unroll
      for (int nn = 0; nn < 4; ++nn) {
        int jrow = w * 64 + nn * 16 + (lane & 15);
        bfr[nn] = *(const bf16x8*)(lB + jrow * 64 + ((sl ^ (jrow & 7)) << 3));
      }
#pragma unroll
      for (int mm = 0; mm < 4; ++mm)
#pragma unroll
        for (int nn = 0; nn < 4; ++nn)
          acc[mm][nn] = __builtin_amdgcn_mfma_f32_16x16x32_bf16(af[mm], bfr[nn],
                                                                acc[mm][nn], 0, 0, 0);
    }
    __syncthreads();
  }

  // epilogue: + z[seg], per-column sum / sumsq (no h store)
  int s0 = 0;
  while (o_s[s0] <= row0) ++s0;
  int e0 = o_s[s0];
  int s1 = (s0 < NSEG - 1) ? s0 + 1 : s0;
  int cl = lane & 15, q = lane >> 4;
#pragma unroll
  for (int nn = 0; nn < 4; ++nn) {
    int col = w * 64 + nn * 16 + cl;
    float zA = z[s0 * NC + col], zB = z[s1 * NC + col];
    float ps = 0.f, pq = 0.f;
#pragma unroll
    for (int mm = 0; mm < 4; ++mm) {
#pragma unroll
      for (int r = 0; r < 4; ++r) {
        int row = row0 + mm * 16 + q * 4 + r;
        float hv = acc[mm][nn][r] + ((row < e0) ? zA : zB);
        ps += hv; pq += hv * hv;
      }
    }
    ps += __shfl_xor(ps, 16, 64); ps += __shfl_xor(ps, 32, 64);
    pq += __shfl_xor(pq, 16, 64); pq += __shfl_xor(pq, 32, 64);
    if (q == 0) { s_sum[col] = ps; s_sq[col] = pq; }   // unique col per wave: no atomics
  }
  __syncthreads();
  atomicAdd(&colsum[t], s_sum[t]);
  atomicAdd(&colsumsq[t], s_sq[t]);
}

// ---- GEMM #2: recompute h, apply BN+ReLU, write out fp32 directly ----
// swapped MFMA operands so each lane owns 4 consecutive cols -> float4 stores
__global__ __launch_bounds__(256) void k_gemm_out(
    const unsigned short* __restrict__ x_bf, const unsigned short* __restrict__ w1t,
    const int* __restrict__ o, const float* __restrict__ z,
    const float* __restrict__ colsum, const float* __restrict__ colsumsq,
    const float* __restrict__ gamma, const float* __restrict__ beta,
    float* __restrict__ out) {
  __shared__ __align__(16) unsigned short lA[64 * 64];
  __shared__ __align__(16) unsigned short lB[256 * 64];
  __shared__ float s_scale[NC], s_shift[NC];
  __shared__ int o_s[NSEG];
  int t = threadIdx.x, lane = t & 63, w = t >> 6;
  int row0 = blockIdx.x * 64;
  {  // BN finalize folded in (colsum/colsumsq complete from previous kernel)
    float invN = 1.f / (float)N_PTS;
    float mu = colsum[t] * invN;
    float var = colsumsq[t] * invN - mu * mu;
    float sc = gamma[t] * rsqrtf(var + BN_EPSF);
    s_scale[t] = sc;
    s_shift[t] = beta[t] - mu * sc;
  }
  if (t < NSEG) o_s[t] = o[t];

  f32x4 acc[4][4] = {};
  for (int kt = 0; kt < 4; ++kt) {
    gll16(x_bf + (size_t)(row0 + (t >> 3)) * NC + kt * 64 + (t & 7) * 8, lA + t * 8);
    gll16(x_bf + (size_t)(row0 + (t >> 3) + 32) * NC + kt * 64 + (t & 7) * 8,
          lA + (t + 256) * 8);
#pragma unroll
    for (int i = 0; i < 8; ++i) {
      int tp = t + i * 256;
      gll16(w1t + (size_t)(tp >> 3) * NC + kt * 64 + (t & 7) * 8, lB + tp * 8);
    }
    __syncthreads();
#pragma unroll
    for (int kk = 0; kk < 2; ++kk) {
      bf16x8 af[4], bfr[4];
      int sl = kk * 4 + (lane >> 4);
#pragma unroll
      for (int mm = 0; mm < 4; ++mm) {
        int r = mm * 16 + (lane & 15);
        af[mm] = *(const bf16x8*)(lA + r * 64 + ((sl ^ (r & 7)) << 3));
      }
#pragma unroll
      for (int nn = 0; nn < 4; ++nn) {
        int jrow = w * 64 + nn * 16 + (lane & 15);
        bfr[nn] = *(const bf16x8*)(lB + jrow * 64 + ((sl ^ (jrow & 7)) << 3));
      }
#pragma unroll
      for (int mm = 0; mm < 4; ++mm)
#pragma unroll
        for (int nn = 0; nn < 4; ++nn)   // swapped: out_row from af's n-slot
          acc[mm][nn] = __builtin_amdgcn_mfma_f32_16x16x32_bf16(bfr[nn], af[mm],
                                                                acc[mm][nn], 0, 0, 0);
    }
    __syncthreads();
  }

  // epilogue: out = relu((h + z)*scale + shift), float4 per (mm,nn)
  int s0 = 0;
  while (o_s[s0] <= row0) ++s0;
  int e0 = o_s[s0];
  int s1 = (s0 < NSEG - 1) ? s0 + 1 : s0;
  int rl = lane & 15, q = lane >> 4;
#pragma unroll
  for (int mm = 0; mm < 4; ++mm) {
    int row = row0 + mm * 16 + rl;
    int sg = (row < e0) ? s0 : s1;
#pragma unroll
    for (int nn = 0; nn < 4; ++nn) {
      int c = w * 64 + nn * 16 + q * 4;
      float4 z4 = *(const float4*)(z + sg * NC + c);
      float4 sc4 = *(const float4*)(s_scale + c);
      float4 sh4 = *(const float4*)(s_shift + c);
      float4 o4;
      o4.x = fmaxf((acc[mm][nn][0] + z4.x) * sc4.x + sh4.x, 0.f);
      o4.y = fmaxf((acc[mm][nn][1] + z4.y) * sc4.y + sh4.y, 0.f);
      o4.z = fmaxf((acc[mm][nn][2] + z4.z) * sc4.z + sh4.z, 0.f);
      o4.w = fmaxf((acc[mm][nn][3] + z4.w) * sc4.w + sh4.w, 0.f);
      *(float4*)(out + (size_t)row * NC + c) = o4;
    }
  }
}

extern "C" void kernel_launch(void* const* d_in, const int* in_sizes, int n_in,
                              void* d_out, int out_size, void* d_ws, size_t ws_size,
                              hipStream_t stream) {
  const float* x = (const float*)d_in[0];
  const int* o = (const int*)d_in[1];
  const float* W1 = (const float*)d_in[2];
  const float* b1 = (const float*)d_in[3];
  const float* W2 = (const float*)d_in[4];
  const float* b2 = (const float*)d_in[5];
  const float* gamma = (const float*)d_in[6];
  const float* beta = (const float*)d_in[7];
  float* out = (float*)d_out;

  char* ws = (char*)d_ws;
  unsigned short* x_bf = (unsigned short*)ws;          // 64 MiB, chunk-swizzled
  char* base2 = ws + 67108864;
  float* seg_sums = (float*)(base2);                   // 16 KiB (zeroed)
  float* colsum   = (float*)(base2 + 16384);           // 1 KiB  (zeroed)
  float* colsumsq = (float*)(base2 + 17408);           // 1 KiB  (zeroed)
  float* z        = (float*)(base2 + 18432);           // 16 KiB
  unsigned short* w1t = (unsigned short*)(base2 + 34816);  // 128 KiB, swizzled

  k_prep<<<34, 256, 0, stream>>>(W1, w1t, seg_sums);   // seg_sums..colsumsq contiguous
  k_segsum_convert<<<2048, 256, 0, stream>>>(x, o, x_bf, seg_sums);
  k_seg_mlp<<<16, 256, 0, stream>>>(o, seg_sums, W1, b1, W2, b2, z);
  k_gemm_stats<<<2048, 256, 0, stream>>>(x_bf, w1t, o, z, colsum, colsumsq);
  k_gemm_out<<<2048, 256, 0, stream>>>(x_bf, w1t, o, z, colsum, colsumsq,
                                       gamma, beta, out);
}

// Round 2
// 346.516 us; speedup vs baseline: 1.0529x; 1.0529x over previous
//
#include <hip/hip_runtime.h>
#include <stdint.h>

#define N_PTS 131072
#define NC 256
#define NSEG 16
#define BN_EPSF 1e-5f

typedef __attribute__((ext_vector_type(8))) short bf16x8;
typedef __attribute__((ext_vector_type(4))) float f32x4;

__device__ __forceinline__ unsigned short f2bf(float f) {
  union { float f; uint32_t u; } v; v.f = f;
  uint32_t u = v.u;
  uint32_t r = (u + 0x7fffu + ((u >> 16) & 1u)) >> 16;
  return (unsigned short)r;
}

// Chunk swizzle: within each 64-col (128B) window of a row, XOR the 8-col
// (16B) chunk index with (row&7). Storage (global x_bf/w1t and LDS) holds
// pre-swizzled chunks; global_load_lds copies verbatim; ds_read_b128 applies
// the same XOR -> 2-way bank aliasing (free) instead of 8-way.
__device__ __forceinline__ int swz(int col, int row) {
  return (col & ~63) | ((((col >> 3) & 7) ^ (row & 7)) << 3) | (col & 7);
}

__device__ __forceinline__ void gll16(const unsigned short* g, unsigned short* l) {
  __builtin_amdgcn_global_load_lds(
      (const __attribute__((address_space(1))) void*)g,
      (__attribute__((address_space(3))) void*)l, 16, 0, 0);
}

// ---- prep: blocks 0..15 transpose+convert+swizzle W1_top; 16..48 zero stats ----
__global__ __launch_bounds__(256) void k_prep(const float* __restrict__ W1,
                                              unsigned short* __restrict__ w1t,
                                              float* __restrict__ zerobuf) {
  int b = blockIdx.x, t = threadIdx.x;
  if (b >= 16) {
    int i = (b - 16) * 256 + t;
    if (i < 8448) zerobuf[i] = 0.f;  // seg_sums(4096)+hseg(4096)+gsumsq(256)
    return;
  }
  __shared__ float tile[64][65];
  int bx = b & 3, by = b >> 2;
  int k0 = by * 64, j0 = bx * 64;
  int r = t >> 6, c = t & 63;
#pragma unroll
  for (int i = 0; i < 16; ++i) {
    int kk = r + i * 4;
    tile[kk][c] = W1[(size_t)(k0 + kk) * NC + j0 + c];
  }
  __syncthreads();
#pragma unroll
  for (int i = 0; i < 16; ++i) {
    int jj = r + i * 4;
    int row = j0 + jj, col = k0 + c;
    w1t[(size_t)row * NC + swz(col, row)] = f2bf(tile[c][jj]);
  }
}

// ---- GEMM #1 (fused): reg-stage x fp32 -> bf16 (LDS + x_bf global),
// per-segment x col sums, g = x@W1_top, emit hseg (per-seg col sums of g)
// and gsumsq (col sums of g^2). No z dependency.
__global__ __launch_bounds__(256) void k_gemm1(
    const float* __restrict__ x, const int* __restrict__ o,
    const unsigned short* __restrict__ w1t,
    unsigned short* __restrict__ x_bf,
    float* __restrict__ seg_sums, float* __restrict__ hseg,
    float* __restrict__ gsumsq) {
  __shared__ __align__(16) unsigned short lA[64 * NC];   // 32 KiB, full-K, swizzled
  __shared__ __align__(16) unsigned short lB[NC * 64];   // 32 KiB, per-kt
  __shared__ float s_acc[2][NC];
  __shared__ float s_hA[NC], s_hB[NC], s_q[NC];
  __shared__ int o_s[NSEG];
  int t = threadIdx.x, lane = t & 63, w = t >> 6;
  int row0 = blockIdx.x * 64;
  if (t < NSEG) o_s[t] = o[t];
  s_acc[0][t] = 0.f;
  s_acc[1][t] = 0.f;
  __syncthreads();
  int c0 = lane * 4;
  int s0 = 0;
  while (o_s[s0] <= row0) ++s0;
  int e0 = o_s[s0];
  int s1 = (s0 < NSEG - 1) ? s0 + 1 : s0;

  // phase 0: 16 coalesced float4 loads/thread; convert; stage lA; write x_bf
  {
    float4 accA = {0.f, 0.f, 0.f, 0.f}, accB = {0.f, 0.f, 0.f, 0.f};
    const float4* xv = (const float4*)x;
#pragma unroll
    for (int i = 0; i < 16; ++i) {
      int rl = w + i * 4;          // local row 0..63
      int r = row0 + rl;           // global row
      float4 v = xv[(size_t)r * 64 + lane];
      ushort4 b;
      b.x = f2bf(v.x); b.y = f2bf(v.y); b.z = f2bf(v.z); b.w = f2bf(v.w);
      int sc = swz(c0, r);         // r ≡ rl (mod 8): same XOR both sides
      *(ushort4*)(x_bf + (size_t)r * NC + sc) = b;
      *(ushort4*)(lA + rl * NC + sc) = b;
      bool inA = (r < e0);
      accA.x += inA ? v.x : 0.f; accB.x += inA ? 0.f : v.x;
      accA.y += inA ? v.y : 0.f; accB.y += inA ? 0.f : v.y;
      accA.z += inA ? v.z : 0.f; accB.z += inA ? 0.f : v.z;
      accA.w += inA ? v.w : 0.f; accB.w += inA ? 0.f : v.w;
    }
    atomicAdd(&s_acc[0][c0 + 0], accA.x);
    atomicAdd(&s_acc[0][c0 + 1], accA.y);
    atomicAdd(&s_acc[0][c0 + 2], accA.z);
    atomicAdd(&s_acc[0][c0 + 3], accA.w);
    atomicAdd(&s_acc[1][c0 + 0], accB.x);
    atomicAdd(&s_acc[1][c0 + 1], accB.y);
    atomicAdd(&s_acc[1][c0 + 2], accB.z);
    atomicAdd(&s_acc[1][c0 + 3], accB.w);
  }

  f32x4 acc[4][4] = {};
  for (int kt = 0; kt < 4; ++kt) {
    // stage B tile [256 cols][64 k] — verbatim copy of swizzled w1t
#pragma unroll
    for (int i = 0; i < 8; ++i) {
      int tp = t + i * 256;
      gll16(w1t + (size_t)(tp >> 3) * NC + kt * 64 + (t & 7) * 8, lB + tp * 8);
    }
    __syncthreads();   // also publishes phase-0 lA writes on first iteration
#pragma unroll
    for (int kk = 0; kk < 2; ++kk) {
      bf16x8 af[4], bfr[4];
      int sl = kk * 4 + (lane >> 4);
#pragma unroll
      for (int mm = 0; mm < 4; ++mm) {
        int r = mm * 16 + (lane & 15);
        af[mm] = *(const bf16x8*)(lA + r * NC + kt * 64 + ((sl ^ (r & 7)) << 3));
      }
#pragma unroll
      for (int nn = 0; nn < 4; ++nn) {
        int jrow = w * 64 + nn * 16 + (lane & 15);
        bfr[nn] = *(const bf16x8*)(lB + jrow * 64 + ((sl ^ (jrow & 7)) << 3));
      }
#pragma unroll
      for (int mm = 0; mm < 4; ++mm)
#pragma unroll
        for (int nn = 0; nn < 4; ++nn)
          acc[mm][nn] = __builtin_amdgcn_mfma_f32_16x16x32_bf16(af[mm], bfr[nn],
                                                                acc[mm][nn], 0, 0, 0);
    }
    __syncthreads();
  }

  // epilogue: per-seg col sums of g (split A/B rows) + col sums of g^2
  int cl = lane & 15, q = lane >> 4;
#pragma unroll
  for (int nn = 0; nn < 4; ++nn) {
    int col = w * 64 + nn * 16 + cl;
    float pA = 0.f, pB = 0.f, pq = 0.f;
#pragma unroll
    for (int mm = 0; mm < 4; ++mm) {
#pragma unroll
      for (int r_ = 0; r_ < 4; ++r_) {
        int row = row0 + mm * 16 + q * 4 + r_;
        float gv = acc[mm][nn][r_];
        bool inA = (row < e0);
        pA += inA ? gv : 0.f;
        pB += inA ? 0.f : gv;
        pq += gv * gv;
      }
    }
    pA += __shfl_xor(pA, 16, 64); pA += __shfl_xor(pA, 32, 64);
    pB += __shfl_xor(pB, 16, 64); pB += __shfl_xor(pB, 32, 64);
    pq += __shfl_xor(pq, 16, 64); pq += __shfl_xor(pq, 32, 64);
    if (q == 0) { s_hA[col] = pA; s_hB[col] = pB; s_q[col] = pq; }
  }
  __syncthreads();
  atomicAdd(&seg_sums[s0 * NC + t], s_acc[0][t]);
  atomicAdd(&seg_sums[s1 * NC + t], s_acc[1][t]);
  atomicAdd(&hseg[s0 * NC + t], s_hA[t]);
  atomicAdd(&hseg[s1 * NC + t], s_hB[t]);
  atomicAdd(&gsumsq[t], s_q[t]);
}

// ---- tiny per-segment MLP: means -> y=relu(means@W2+b2) -> z=y@W1_bot+b1 ----
__global__ __launch_bounds__(256) void k_seg_mlp(
    const int* __restrict__ o, const float* __restrict__ seg_sums,
    const float* __restrict__ W1, const float* __restrict__ b1,
    const float* __restrict__ W2, const float* __restrict__ b2,
    float* __restrict__ z) {
  __shared__ float mean_s[NC];
  __shared__ float y_s[NC];
  int b = blockIdx.x, j = threadIdx.x;
  int start = (b == 0) ? 0 : o[b - 1];
  float inv = 1.f / (float)(o[b] - start);
  mean_s[j] = seg_sums[b * NC + j] * inv;
  __syncthreads();
  float a = b2[j];
  for (int k = 0; k < NC; ++k) a += mean_s[k] * W2[k * NC + j];
  y_s[j] = fmaxf(a, 0.f);
  __syncthreads();
  float a2 = b1[j];
  for (int k = 0; k < NC; ++k) a2 += y_s[k] * W1[(NC + k) * NC + j];
  z[b * NC + j] = a2;
}

// ---- GEMM #2: BN finalize (decomposed stats) in prologue; recompute g;
// out = relu((g + z[seg])*scale + shift) written fp32 directly.
__global__ __launch_bounds__(256) void k_gemm2(
    const unsigned short* __restrict__ x_bf, const unsigned short* __restrict__ w1t,
    const int* __restrict__ o, const float* __restrict__ z,
    const float* __restrict__ hseg, const float* __restrict__ gsumsq,
    const float* __restrict__ gamma, const float* __restrict__ beta,
    float* __restrict__ out) {
  __shared__ __align__(16) unsigned short lA[64 * NC];
  __shared__ __align__(16) unsigned short lB[NC * 64];
  __shared__ float s_scale[NC], s_shift[NC];
  __shared__ int o_s[NSEG];
  int t = threadIdx.x, lane = t & 63, w = t >> 6;
  int row0 = blockIdx.x * 64;
  if (t < NSEG) o_s[t] = o[t];
  __syncthreads();
  {  // BN finalize: colsum = Σ hseg + Σ cnt·z ; colsumsq = gsumsq + Σ(2·hseg+cnt·z)·z
    float cs = 0.f, cq = gsumsq[t];
    int prev = 0;
#pragma unroll
    for (int s = 0; s < NSEG; ++s) {
      float cnt = (float)(o_s[s] - prev);
      prev = o_s[s];
      float hs = hseg[s * NC + t], zz = z[s * NC + t];
      cs += hs + cnt * zz;
      cq += (2.f * hs + cnt * zz) * zz;
    }
    float invN = 1.f / (float)N_PTS;
    float mu = cs * invN;
    float var = cq * invN - mu * mu;
    float sc = gamma[t] * rsqrtf(var + BN_EPSF);
    s_scale[t] = sc;
    s_shift[t] = beta[t] - mu * sc;
  }
  // stage full-K A tile once (verbatim copy of swizzled x_bf rows)
#pragma unroll
  for (int i = 0; i < 8; ++i) {
    int tp = t + i * 256;
    gll16(x_bf + (size_t)(row0 + (tp >> 5)) * NC + (tp & 31) * 8, lA + tp * 8);
  }
  f32x4 acc[4][4] = {};
  for (int kt = 0; kt < 4; ++kt) {
#pragma unroll
    for (int i = 0; i < 8; ++i) {
      int tp = t + i * 256;
      gll16(w1t + (size_t)(tp >> 3) * NC + kt * 64 + (t & 7) * 8, lB + tp * 8);
    }
    __syncthreads();
#pragma unroll
    for (int kk = 0; kk < 2; ++kk) {
      bf16x8 af[4], bfr[4];
      int sl = kk * 4 + (lane >> 4);
#pragma unroll
      for (int mm = 0; mm < 4; ++mm) {
        int r = mm * 16 + (lane & 15);
        af[mm] = *(const bf16x8*)(lA + r * NC + kt * 64 + ((sl ^ (r & 7)) << 3));
      }
#pragma unroll
      for (int nn = 0; nn < 4; ++nn) {
        int jrow = w * 64 + nn * 16 + (lane & 15);
        bfr[nn] = *(const bf16x8*)(lB + jrow * 64 + ((sl ^ (jrow & 7)) << 3));
      }
#pragma unroll
      for (int mm = 0; mm < 4; ++mm)
#pragma unroll
        for (int nn = 0; nn < 4; ++nn)   // swapped operands: lane owns 4 consecutive cols
          acc[mm][nn] = __builtin_amdgcn_mfma_f32_16x16x32_bf16(bfr[nn], af[mm],
                                                                acc[mm][nn], 0, 0, 0);
    }
    __syncthreads();
  }
  // epilogue: out = relu((g + z)*scale + shift), float4 stores
  int s0 = 0;
  while (o_s[s0] <= row0) ++s0;
  int e0 = o_s[s0];
  int s1 = (s0 < NSEG - 1) ? s0 + 1 : s0;
  int rl = lane & 15, q = lane >> 4;
#pragma unroll
  for (int mm = 0; mm < 4; ++mm) {
    int row = row0 + mm * 16 + rl;
    int sg = (row < e0) ? s0 : s1;
#pragma unroll
    for (int nn = 0; nn < 4; ++nn) {
      int c = w * 64 + nn * 16 + q * 4;
      float4 z4 = *(const float4*)(z + sg * NC + c);
      float4 sc4 = *(const float4*)(s_scale + c);
      float4 sh4 = *(const float4*)(s_shift + c);
      float4 o4;
      o4.x = fmaxf((acc[mm][nn][0] + z4.x) * sc4.x + sh4.x, 0.f);
      o4.y = fmaxf((acc[mm][nn][1] + z4.y) * sc4.y + sh4.y, 0.f);
      o4.z = fmaxf((acc[mm][nn][2] + z4.z) * sc4.z + sh4.z, 0.f);
      o4.w = fmaxf((acc[mm][nn][3] + z4.w) * sc4.w + sh4.w, 0.f);
      *(float4*)(out + (size_t)row * NC + c) = o4;
    }
  }
}

extern "C" void kernel_launch(void* const* d_in, const int* in_sizes, int n_in,
                              void* d_out, int out_size, void* d_ws, size_t ws_size,
                              hipStream_t stream) {
  const float* x = (const float*)d_in[0];
  const int* o = (const int*)d_in[1];
  const float* W1 = (const float*)d_in[2];
  const float* b1 = (const float*)d_in[3];
  const float* W2 = (const float*)d_in[4];
  const float* b2 = (const float*)d_in[5];
  const float* gamma = (const float*)d_in[6];
  const float* beta = (const float*)d_in[7];
  float* out = (float*)d_out;

  char* ws = (char*)d_ws;
  unsigned short* x_bf = (unsigned short*)ws;          // 64 MiB, chunk-swizzled
  char* base2 = ws + 67108864;
  float* seg_sums = (float*)(base2);                   // 16 KiB (zeroed)
  float* hseg     = (float*)(base2 + 16384);           // 16 KiB (zeroed)
  float* gsumsq   = (float*)(base2 + 32768);           // 1 KiB  (zeroed)
  float* z        = (float*)(base2 + 33792);           // 16 KiB
  unsigned short* w1t = (unsigned short*)(base2 + 50176);  // 128 KiB, swizzled

  k_prep<<<49, 256, 0, stream>>>(W1, w1t, seg_sums);   // zeroes seg_sums..gsumsq
  k_gemm1<<<2048, 256, 0, stream>>>(x, o, w1t, x_bf, seg_sums, hseg, gsumsq);
  k_seg_mlp<<<16, 256, 0, stream>>>(o, seg_sums, W1, b1, W2, b2, z);
  k_gemm2<<<2048, 256, 0, stream>>>(x_bf, w1t, o, z, hseg, gsumsq,
                                    gamma, beta, out);
}

// Round 3
// 346.396 us; speedup vs baseline: 1.0533x; 1.0003x over previous
//
#include <hip/hip_runtime.h>
#include <stdint.h>

#define N_PTS 131072
#define NC 256
#define NSEG 16
#define BN_EPSF 1e-5f

typedef __attribute__((ext_vector_type(8))) short bf16x8;
typedef __attribute__((ext_vector_type(4))) float f32x4;

__device__ __forceinline__ unsigned short f2bf(float f) {
  union { float f; uint32_t u; } v; v.f = f;
  uint32_t u = v.u;
  uint32_t r = (u + 0x7fffu + ((u >> 16) & 1u)) >> 16;
  return (unsigned short)r;
}
__device__ __forceinline__ float bf2f(unsigned short h) {
  union { uint32_t u; float f; } v; v.u = ((uint32_t)h) << 16; return v.f;
}

// Chunk swizzle: within each 64-col (128B) window of a row, XOR the 8-col
// (16B) chunk index with (row&7). w1t global storage and LDS hold pre-swizzled
// chunks; global_load_lds copies verbatim; ds_read_b128 applies the same XOR.
__device__ __forceinline__ int swz(int col, int row) {
  return (col & ~63) | ((((col >> 3) & 7) ^ (row & 7)) << 3) | (col & 7);
}

__device__ __forceinline__ void gll16(const unsigned short* g, unsigned short* l) {
  __builtin_amdgcn_global_load_lds(
      (const __attribute__((address_space(1))) void*)g,
      (__attribute__((address_space(3))) void*)l, 16, 0, 0);
}

// ---- prep: blocks 0..15 transpose+convert+swizzle W1_top; 16..48 zero stats ----
__global__ __launch_bounds__(256) void k_prep(const float* __restrict__ W1,
                                              unsigned short* __restrict__ w1t,
                                              float* __restrict__ zerobuf) {
  int b = blockIdx.x, t = threadIdx.x;
  if (b >= 16) {
    int i = (b - 16) * 256 + t;
    if (i < 8448) zerobuf[i] = 0.f;  // seg_sums(4096)+hseg(4096)+gsumsq(256)
    return;
  }
  __shared__ float tile[64][65];
  int bx = b & 3, by = b >> 2;
  int k0 = by * 64, j0 = bx * 64;
  int r = t >> 6, c = t & 63;
#pragma unroll
  for (int i = 0; i < 16; ++i) {
    int kk = r + i * 4;
    tile[kk][c] = W1[(size_t)(k0 + kk) * NC + j0 + c];
  }
  __syncthreads();
#pragma unroll
  for (int i = 0; i < 16; ++i) {
    int jj = r + i * 4;
    int row = j0 + jj, col = k0 + c;
    w1t[(size_t)row * NC + swz(col, row)] = f2bf(tile[c][jj]);
  }
}

// ---- GEMM (fused, the only big one): reg-stage x fp32 -> bf16 LDS,
// per-segment x col sums, g = x@W1_top (swapped MFMA: lane owns 4 consecutive
// cols), write g_bf, emit hseg (per-seg col sums of g) + gsumsq (col Σg²).
// 512 threads / 8 waves; wave w owns cols [w*32, w*32+32); 2 blocks/CU.
__global__ __launch_bounds__(512, 4) void k_gemm1(
    const float* __restrict__ x, const int* __restrict__ o,
    const unsigned short* __restrict__ w1t,
    unsigned short* __restrict__ g_bf,
    float* __restrict__ seg_sums, float* __restrict__ hseg,
    float* __restrict__ gsumsq) {
  __shared__ __align__(16) unsigned short lA[64 * NC];   // 32 KiB full-K, swizzled
  __shared__ __align__(16) unsigned short lB[NC * 64];   // 32 KiB per-kt
  __shared__ float s_acc[2][NC];
  __shared__ float s_hA[NC], s_hB[NC], s_q[NC];
  __shared__ int o_s[NSEG];
  int t = threadIdx.x, lane = t & 63, w = t >> 6;
  int row0 = blockIdx.x * 64;
  if (t < NSEG) o_s[t] = o[t];
  if (t < NC) { s_acc[0][t] = 0.f; s_acc[1][t] = 0.f; }
  __syncthreads();

  // issue B staging for kt=0 FIRST: its L2 latency hides under x HBM loads
#pragma unroll
  for (int i = 0; i < 4; ++i) {
    int tp = t + i * 512;
    gll16(w1t + (size_t)(tp >> 3) * NC + (tp & 7) * 8, lB + tp * 8);
  }

  int c0 = lane * 4;
  int s0 = 0;
  while (o_s[s0] <= row0) ++s0;
  int e0 = o_s[s0];
  int s1 = (s0 < NSEG - 1) ? s0 + 1 : s0;

  // phase 0: 8 coalesced float4 loads/thread; convert; stage lA; seg sums
  {
    float4 accA = {0.f, 0.f, 0.f, 0.f}, accB = {0.f, 0.f, 0.f, 0.f};
    const float4* xv = (const float4*)x;
#pragma unroll
    for (int i = 0; i < 8; ++i) {
      int rl = w + i * 8;          // local row 0..63 (wave-uniform per iter)
      int r = row0 + rl;
      float4 v = xv[(size_t)r * 64 + lane];
      ushort4 b;
      b.x = f2bf(v.x); b.y = f2bf(v.y); b.z = f2bf(v.z); b.w = f2bf(v.w);
      *(ushort4*)(lA + rl * NC + swz(c0, rl)) = b;
      bool inA = (r < e0);
      accA.x += inA ? v.x : 0.f; accB.x += inA ? 0.f : v.x;
      accA.y += inA ? v.y : 0.f; accB.y += inA ? 0.f : v.y;
      accA.z += inA ? v.z : 0.f; accB.z += inA ? 0.f : v.z;
      accA.w += inA ? v.w : 0.f; accB.w += inA ? 0.f : v.w;
    }
    atomicAdd(&s_acc[0][c0 + 0], accA.x);
    atomicAdd(&s_acc[0][c0 + 1], accA.y);
    atomicAdd(&s_acc[0][c0 + 2], accA.z);
    atomicAdd(&s_acc[0][c0 + 3], accA.w);
    atomicAdd(&s_acc[1][c0 + 0], accB.x);
    atomicAdd(&s_acc[1][c0 + 1], accB.y);
    atomicAdd(&s_acc[1][c0 + 2], accB.z);
    atomicAdd(&s_acc[1][c0 + 3], accB.w);
  }

  f32x4 acc[4][2] = {};
  for (int kt = 0; kt < 4; ++kt) {
    if (kt > 0) {
#pragma unroll
      for (int i = 0; i < 4; ++i) {
        int tp = t + i * 512;
        gll16(w1t + (size_t)(tp >> 3) * NC + kt * 64 + (tp & 7) * 8, lB + tp * 8);
      }
    }
    __syncthreads();  // publishes lB(kt) (+ lA on first iter)
#pragma unroll
    for (int kk = 0; kk < 2; ++kk) {
      bf16x8 af[4], bfr[2];
      int sl = kk * 4 + (lane >> 4);
#pragma unroll
      for (int mm = 0; mm < 4; ++mm) {
        int r = mm * 16 + (lane & 15);
        af[mm] = *(const bf16x8*)(lA + r * NC + kt * 64 + ((sl ^ (r & 7)) << 3));
      }
#pragma unroll
      for (int nn = 0; nn < 2; ++nn) {
        int jrow = w * 32 + nn * 16 + (lane & 15);
        bfr[nn] = *(const bf16x8*)(lB + jrow * 64 + ((sl ^ (jrow & 7)) << 3));
      }
#pragma unroll
      for (int mm = 0; mm < 4; ++mm)
#pragma unroll
        for (int nn = 0; nn < 2; ++nn)   // swapped: lane owns rows at l&15, 4 cols/reg
          acc[mm][nn] = __builtin_amdgcn_mfma_f32_16x16x32_bf16(bfr[nn], af[mm],
                                                                acc[mm][nn], 0, 0, 0);
    }
    __syncthreads();  // release lB
  }

  // epilogue: write g_bf (pre-z), per-seg col sums of g, col Σg²
  int rl = lane & 15, q = lane >> 4;
#pragma unroll
  for (int nn = 0; nn < 2; ++nn) {
    float tA[4] = {0.f, 0.f, 0.f, 0.f};
    float tB[4] = {0.f, 0.f, 0.f, 0.f};
    float tq[4] = {0.f, 0.f, 0.f, 0.f};
#pragma unroll
    for (int mm = 0; mm < 4; ++mm) {
      int row = row0 + mm * 16 + rl;
      bool inA = (row < e0);
      ushort4 b;
#pragma unroll
      for (int r = 0; r < 4; ++r) {
        float gv = acc[mm][nn][r];
        tA[r] += inA ? gv : 0.f;
        tB[r] += inA ? 0.f : gv;
        tq[r] += gv * gv;
        ((unsigned short*)&b)[r] = f2bf(gv);
      }
      *(ushort4*)(g_bf + (size_t)row * NC + w * 32 + nn * 16 + q * 4) = b;
    }
#pragma unroll
    for (int r = 0; r < 4; ++r) {
      tA[r] += __shfl_xor(tA[r], 1, 64); tA[r] += __shfl_xor(tA[r], 2, 64);
      tA[r] += __shfl_xor(tA[r], 4, 64); tA[r] += __shfl_xor(tA[r], 8, 64);
      tB[r] += __shfl_xor(tB[r], 1, 64); tB[r] += __shfl_xor(tB[r], 2, 64);
      tB[r] += __shfl_xor(tB[r], 4, 64); tB[r] += __shfl_xor(tB[r], 8, 64);
      tq[r] += __shfl_xor(tq[r], 1, 64); tq[r] += __shfl_xor(tq[r], 2, 64);
      tq[r] += __shfl_xor(tq[r], 4, 64); tq[r] += __shfl_xor(tq[r], 8, 64);
    }
    if (rl == 0) {
#pragma unroll
      for (int r = 0; r < 4; ++r) {
        int col = w * 32 + nn * 16 + q * 4 + r;
        s_hA[col] = tA[r]; s_hB[col] = tB[r]; s_q[col] = tq[r];
      }
    }
  }
  __syncthreads();
  if (t < NC) {
    atomicAdd(&seg_sums[s0 * NC + t], s_acc[0][t]);
    atomicAdd(&seg_sums[s1 * NC + t], s_acc[1][t]);
    atomicAdd(&hseg[s0 * NC + t], s_hA[t]);
    atomicAdd(&hseg[s1 * NC + t], s_hB[t]);
    atomicAdd(&gsumsq[t], s_q[t]);
  }
}

// ---- tiny per-segment MLP: means -> y=relu(means@W2+b2) -> z=y@W1_bot+b1 ----
__global__ __launch_bounds__(256) void k_seg_mlp(
    const int* __restrict__ o, const float* __restrict__ seg_sums,
    const float* __restrict__ W1, const float* __restrict__ b1,
    const float* __restrict__ W2, const float* __restrict__ b2,
    float* __restrict__ z) {
  __shared__ float mean_s[NC];
  __shared__ float y_s[NC];
  int b = blockIdx.x, j = threadIdx.x;
  int start = (b == 0) ? 0 : o[b - 1];
  float inv = 1.f / (float)(o[b] - start);
  mean_s[j] = seg_sums[b * NC + j] * inv;
  __syncthreads();
  float a = b2[j];
  for (int k = 0; k < NC; ++k) a += mean_s[k] * W2[k * NC + j];
  y_s[j] = fmaxf(a, 0.f);
  __syncthreads();
  float a2 = b1[j];
  for (int k = 0; k < NC; ++k) a2 += y_s[k] * W1[(NC + k) * NC + j];
  z[b * NC + j] = a2;
}

// ---- apply: BN finalize (decomposed stats) + out = relu((g+z[seg])*sc+sh) ----
__global__ __launch_bounds__(256) void k_apply(
    const unsigned short* __restrict__ g_bf, const int* __restrict__ o,
    const float* __restrict__ z, const float* __restrict__ hseg,
    const float* __restrict__ gsumsq, const float* __restrict__ gamma,
    const float* __restrict__ beta, float* __restrict__ out) {
  __shared__ float s_scale[NC], s_shift[NC];
  __shared__ int o_s[NSEG];
  int t = threadIdx.x;
  int row0 = blockIdx.x * 64;
  if (t < NSEG) o_s[t] = o[t];
  __syncthreads();
  {  // colsum = Σ hseg + Σ cnt·z ; colsumsq = gsumsq + Σ(2·hseg+cnt·z)·z
    float cs = 0.f, cq = gsumsq[t];
    int prev = 0;
#pragma unroll
    for (int s = 0; s < NSEG; ++s) {
      float cnt = (float)(o_s[s] - prev);
      prev = o_s[s];
      float hs = hseg[s * NC + t], zz = z[s * NC + t];
      cs += hs + cnt * zz;
      cq += (2.f * hs + cnt * zz) * zz;
    }
    float invN = 1.f / (float)N_PTS;
    float mu = cs * invN;
    float var = cq * invN - mu * mu;
    float sc = gamma[t] * rsqrtf(var + BN_EPSF);
    s_scale[t] = sc;
    s_shift[t] = beta[t] - mu * sc;
  }
  __syncthreads();
  int s0 = 0;
  while (o_s[s0] <= row0) ++s0;
  int e0 = o_s[s0];
  int s1 = (s0 < NSEG - 1) ? s0 + 1 : s0;
  int cg = (t & 31) * 8, rsub = t >> 5;
  float4 sc0 = *(const float4*)(s_scale + cg), sc1 = *(const float4*)(s_scale + cg + 4);
  float4 sh0 = *(const float4*)(s_shift + cg), sh1 = *(const float4*)(s_shift + cg + 4);
  float4 zA0 = *(const float4*)(z + s0 * NC + cg), zA1 = *(const float4*)(z + s0 * NC + cg + 4);
  float4 zB0 = *(const float4*)(z + s1 * NC + cg), zB1 = *(const float4*)(z + s1 * NC + cg + 4);
#pragma unroll
  for (int i = 0; i < 8; ++i) {
    int row = row0 + rsub + i * 8;
    uint4 hv = *(const uint4*)(g_bf + (size_t)row * NC + cg);
    bool inA = (row < e0);
    float4 z0 = inA ? zA0 : zB0;
    float4 z1 = inA ? zA1 : zB1;
    float4 o0, o1;
    o0.x = fmaxf((bf2f((unsigned short)(hv.x & 0xffffu)) + z0.x) * sc0.x + sh0.x, 0.f);
    o0.y = fmaxf((bf2f((unsigned short)(hv.x >> 16)) + z0.y) * sc0.y + sh0.y, 0.f);
    o0.z = fmaxf((bf2f((unsigned short)(hv.y & 0xffffu)) + z0.z) * sc0.z + sh0.z, 0.f);
    o0.w = fmaxf((bf2f((unsigned short)(hv.y >> 16)) + z0.w) * sc0.w + sh0.w, 0.f);
    o1.x = fmaxf((bf2f((unsigned short)(hv.z & 0xffffu)) + z1.x) * sc1.x + sh1.x, 0.f);
    o1.y = fmaxf((bf2f((unsigned short)(hv.z >> 16)) + z1.y) * sc1.y + sh1.y, 0.f);
    o1.z = fmaxf((bf2f((unsigned short)(hv.w & 0xffffu)) + z1.z) * sc1.z + sh1.z, 0.f);
    o1.w = fmaxf((bf2f((unsigned short)(hv.w >> 16)) + z1.w) * sc1.w + sh1.w, 0.f);
    *(float4*)(out + (size_t)row * NC + cg) = o0;
    *(float4*)(out + (size_t)row * NC + cg + 4) = o1;
  }
}

extern "C" void kernel_launch(void* const* d_in, const int* in_sizes, int n_in,
                              void* d_out, int out_size, void* d_ws, size_t ws_size,
                              hipStream_t stream) {
  const float* x = (const float*)d_in[0];
  const int* o = (const int*)d_in[1];
  const float* W1 = (const float*)d_in[2];
  const float* b1 = (const float*)d_in[3];
  const float* W2 = (const float*)d_in[4];
  const float* b2 = (const float*)d_in[5];
  const float* gamma = (const float*)d_in[6];
  const float* beta = (const float*)d_in[7];
  float* out = (float*)d_out;

  char* ws = (char*)d_ws;
  unsigned short* g_bf = (unsigned short*)ws;          // 64 MiB
  char* base2 = ws + 67108864;
  float* seg_sums = (float*)(base2);                   // 16 KiB (zeroed)
  float* hseg     = (float*)(base2 + 16384);           // 16 KiB (zeroed)
  float* gsumsq   = (float*)(base2 + 32768);           // 1 KiB  (zeroed)
  float* z        = (float*)(base2 + 33792);           // 16 KiB
  unsigned short* w1t = (unsigned short*)(base2 + 50176);  // 128 KiB, swizzled

  k_prep<<<49, 256, 0, stream>>>(W1, w1t, seg_sums);   // zeroes seg_sums..gsumsq
  k_gemm1<<<2048, 512, 0, stream>>>(x, o, w1t, g_bf, seg_sums, hseg, gsumsq);
  k_seg_mlp<<<16, 256, 0, stream>>>(o, seg_sums, W1, b1, W2, b2, z);
  k_apply<<<2048, 256, 0, stream>>>(g_bf, o, z, hseg, gsumsq, gamma, beta, out);
}

// Round 5
// 311.602 us; speedup vs baseline: 1.1709x; 1.1117x over previous
//
#include <hip/hip_runtime.h>
#include <stdint.h>

#define N_PTS 131072
#define NC 256
#define NSEG 16
#define BN_EPSF 1e-5f

typedef __attribute__((ext_vector_type(8))) short bf16x8;
typedef __attribute__((ext_vector_type(4))) float f32x4;

__device__ __forceinline__ unsigned short f2bf(float f) {
  union { float f; uint32_t u; } v; v.f = f;
  uint32_t u = v.u;
  uint32_t r = (u + 0x7fffu + ((u >> 16) & 1u)) >> 16;
  return (unsigned short)r;
}
__device__ __forceinline__ float bf2f(unsigned short h) {
  union { uint32_t u; float f; } v; v.u = ((uint32_t)h) << 16; return v.f;
}

// Chunk swizzle for lA only: within each 64-col (128B) window of a row, XOR
// the 8-col (16B) chunk index with (row&7). Writes pre-swizzle, ds_read_b128
// applies the same XOR -> 2-way bank aliasing (free) instead of 8/16-way.
__device__ __forceinline__ int swz(int col, int row) {
  return (col & ~63) | ((((col >> 3) & 7) ^ (row & 7)) << 3) | (col & 7);
}

// ---- prep: blocks 0..15 transpose+convert W1_top (plain layout); 16.. zero stats ----
__global__ __launch_bounds__(256) void k_prep(const float* __restrict__ W1,
                                              unsigned short* __restrict__ w1t,
                                              float* __restrict__ zerobuf) {
  int b = blockIdx.x, t = threadIdx.x;
  if (b >= 16) {
    int i = (b - 16) * 256 + t;
    if (i < 8448) zerobuf[i] = 0.f;  // seg_sums(4096)+hseg(4096)+gsumsq(256)
    return;
  }
  __shared__ float tile[64][65];
  int bx = b & 3, by = b >> 2;
  int k0 = by * 64, j0 = bx * 64;
  int r = t >> 6, c = t & 63;
#pragma unroll
  for (int i = 0; i < 16; ++i) {
    int kk = r + i * 4;
    tile[kk][c] = W1[(size_t)(k0 + kk) * NC + j0 + c];
  }
  __syncthreads();
#pragma unroll
  for (int i = 0; i < 16; ++i) {
    int jj = r + i * 4;
    w1t[(size_t)(j0 + jj) * NC + k0 + c] = f2bf(tile[c][jj]);  // plain [col][k]
  }
}

// ---- GEMM (persistent-tile pipeline): 512 blocks x 512 thr (8 waves),
// block owns 4 consecutive 64-row tiles (256 rows -> at most ONE segment
// boundary: per-block constant sA,sB,e). B=w1t lives in registers (16 frags).
// lA double-buffered; 1 barrier/tile; x HBM loads for tile t+1 overlap MFMA(t).
__global__ __launch_bounds__(512, 2) void k_gemm1(
    const float* __restrict__ x, const int* __restrict__ o,
    const unsigned short* __restrict__ w1t,
    unsigned short* __restrict__ g_bf,
    float* __restrict__ seg_sums, float* __restrict__ hseg,
    float* __restrict__ gsumsq) {
  __shared__ __align__(16) unsigned short lA[2][64 * NC];   // 2 x 32 KiB, swizzled
  __shared__ float s_xacc[2][NC];
  __shared__ float s_gA[NC], s_gB[NC], s_gq[NC];
  __shared__ int o_s[NSEG];
  int t = threadIdx.x, lane = t & 63, w = t >> 6;
  int rowB = blockIdx.x * 256;
  if (t < NSEG) o_s[t] = o[t];
  if (t < NC) { s_xacc[0][t] = 0.f; s_xacc[1][t] = 0.f; }
  __syncthreads();
  int sA = 0;
  while (o_s[sA] <= rowB) ++sA;
  int e = o_s[sA];
  int sB = (sA < NSEG - 1) ? sA + 1 : sA;

  // B fragments in registers, loaded once (w1t is L2-resident, 128 KiB)
  bf16x8 Bf[4][2][2];  // [kt][kk][nn]
  {
    int jr0 = w * 32 + (lane & 15);
    int sl0 = lane >> 4;
#pragma unroll
    for (int kt = 0; kt < 4; ++kt)
#pragma unroll
      for (int kk = 0; kk < 2; ++kk)
#pragma unroll
        for (int nn = 0; nn < 2; ++nn)
          Bf[kt][kk][nn] = *(const bf16x8*)(
              w1t + (size_t)(jr0 + nn * 16) * NC + kt * 64 + (kk * 4 + sl0) * 8);
  }

  float4 xaccA = {0.f, 0.f, 0.f, 0.f}, xaccB = {0.f, 0.f, 0.f, 0.f};
  f32x4 pA[2] = {}, pB[2] = {}, pq[2] = {};
  f32x4 acc[4][2] = {};
  const float4* xv = (const float4*)x;
  int c0 = lane * 4;
  float4 xr[8];
  // preload tile 0 (8 coalesced float4/thread; wave w covers rows w+8i)
#pragma unroll
  for (int i = 0; i < 8; ++i)
    xr[i] = xv[(size_t)(rowB + w + i * 8) * 64 + lane];

  for (int tile = 0; tile < 4; ++tile) {
    int row0 = rowB + tile * 64;
    int buf = tile & 1;
    // convert + x seg-sums + stage current tile into lA[buf]
#pragma unroll
    for (int i = 0; i < 8; ++i) {
      int rl = w + i * 8;
      int r = row0 + rl;
      float4 v = xr[i];
      ushort4 b;
      b.x = f2bf(v.x); b.y = f2bf(v.y); b.z = f2bf(v.z); b.w = f2bf(v.w);
      *(ushort4*)(&lA[buf][rl * NC + swz(c0, rl)]) = b;
      bool inA = (r < e);
      xaccA.x += inA ? v.x : 0.f; xaccB.x += inA ? 0.f : v.x;
      xaccA.y += inA ? v.y : 0.f; xaccB.y += inA ? 0.f : v.y;
      xaccA.z += inA ? v.z : 0.f; xaccB.z += inA ? 0.f : v.z;
      xaccA.w += inA ? v.w : 0.f; xaccB.w += inA ? 0.f : v.w;
    }
    // issue HBM loads for next tile; they stay in flight under this tile's MFMA
    if (tile < 3) {
#pragma unroll
      for (int i = 0; i < 8; ++i)
        xr[i] = xv[(size_t)(row0 + 64 + w + i * 8) * 64 + lane];
    }
    __syncthreads();  // publish lA[buf]; (buf^1 writes next iter can't race: other buffer)

    // 32 ds_read_b128 + 32 MFMA per wave
#pragma unroll
    for (int kt = 0; kt < 4; ++kt)
#pragma unroll
      for (int kk = 0; kk < 2; ++kk) {
        bf16x8 af[4];
        int sl = kk * 4 + (lane >> 4);
#pragma unroll
        for (int mm = 0; mm < 4; ++mm) {
          int r = mm * 16 + (lane & 15);
          af[mm] = *(const bf16x8*)(&lA[buf][r * NC + kt * 64 + ((sl ^ (r & 7)) << 3)]);
        }
#pragma unroll
        for (int mm = 0; mm < 4; ++mm)
#pragma unroll
          for (int nn = 0; nn < 2; ++nn)
            acc[mm][nn] = __builtin_amdgcn_mfma_f32_16x16x32_bf16(
                Bf[kt][kk][nn], af[mm], acc[mm][nn], 0, 0, 0);
      }

    // per-tile epilogue: g_bf store + reg-accumulated stats, reset acc
    int rl = lane & 15, q = lane >> 4;
#pragma unroll
    for (int mm = 0; mm < 4; ++mm) {
      int row = row0 + mm * 16 + rl;
      bool inA = (row < e);
#pragma unroll
      for (int nn = 0; nn < 2; ++nn) {
        f32x4 g = acc[mm][nn];
        ushort4 b;
        b.x = f2bf(g[0]); b.y = f2bf(g[1]); b.z = f2bf(g[2]); b.w = f2bf(g[3]);
        *(ushort4*)(g_bf + (size_t)row * NC + w * 32 + nn * 16 + q * 4) = b;
        if (inA) pA[nn] += g; else pB[nn] += g;
        pq[nn] += g * g;
        acc[mm][nn] = (f32x4){0.f, 0.f, 0.f, 0.f};
      }
    }
  }

  // block-level flush (once)
  atomicAdd(&s_xacc[0][c0 + 0], xaccA.x);
  atomicAdd(&s_xacc[0][c0 + 1], xaccA.y);
  atomicAdd(&s_xacc[0][c0 + 2], xaccA.z);
  atomicAdd(&s_xacc[0][c0 + 3], xaccA.w);
  atomicAdd(&s_xacc[1][c0 + 0], xaccB.x);
  atomicAdd(&s_xacc[1][c0 + 1], xaccB.y);
  atomicAdd(&s_xacc[1][c0 + 2], xaccB.z);
  atomicAdd(&s_xacc[1][c0 + 3], xaccB.w);
#pragma unroll
  for (int nn = 0; nn < 2; ++nn)
#pragma unroll
    for (int j = 0; j < 4; ++j) {
      float a = pA[nn][j], bb = pB[nn][j], qq = pq[nn][j];
      a += __shfl_xor(a, 1, 64); a += __shfl_xor(a, 2, 64);
      a += __shfl_xor(a, 4, 64); a += __shfl_xor(a, 8, 64);
      bb += __shfl_xor(bb, 1, 64); bb += __shfl_xor(bb, 2, 64);
      bb += __shfl_xor(bb, 4, 64); bb += __shfl_xor(bb, 8, 64);
      qq += __shfl_xor(qq, 1, 64); qq += __shfl_xor(qq, 2, 64);
      qq += __shfl_xor(qq, 4, 64); qq += __shfl_xor(qq, 8, 64);
      pA[nn][j] = a; pB[nn][j] = bb; pq[nn][j] = qq;
    }
  if ((lane & 15) == 0) {
    int q = lane >> 4;
#pragma unroll
    for (int nn = 0; nn < 2; ++nn) {
      int cb = w * 32 + nn * 16 + q * 4;   // wave-exclusive cols: plain stores
#pragma unroll
      for (int j = 0; j < 4; ++j) {
        s_gA[cb + j] = pA[nn][j];
        s_gB[cb + j] = pB[nn][j];
        s_gq[cb + j] = pq[nn][j];
      }
    }
  }
  __syncthreads();
  if (t < NC) {
    atomicAdd(&seg_sums[sA * NC + t], s_xacc[0][t]);
    atomicAdd(&seg_sums[sB * NC + t], s_xacc[1][t]);
    atomicAdd(&hseg[sA * NC + t], s_gA[t]);
    atomicAdd(&hseg[sB * NC + t], s_gB[t]);
    atomicAdd(&gsumsq[t], s_gq[t]);
  }
}

// ---- tiny per-segment MLP: means -> y=relu(means@W2+b2) -> z=y@W1_bot+b1 ----
__global__ __launch_bounds__(256) void k_seg_mlp(
    const int* __restrict__ o, const float* __restrict__ seg_sums,
    const float* __restrict__ W1, const float* __restrict__ b1,
    const float* __restrict__ W2, const float* __restrict__ b2,
    float* __restrict__ z) {
  __shared__ float mean_s[NC];
  __shared__ float y_s[NC];
  int b = blockIdx.x, j = threadIdx.x;
  int start = (b == 0) ? 0 : o[b - 1];
  float inv = 1.f / (float)(o[b] - start);
  mean_s[j] = seg_sums[b * NC + j] * inv;
  __syncthreads();
  float a = b2[j];
  for (int k = 0; k < NC; ++k) a += mean_s[k] * W2[k * NC + j];
  y_s[j] = fmaxf(a, 0.f);
  __syncthreads();
  float a2 = b1[j];
  for (int k = 0; k < NC; ++k) a2 += y_s[k] * W1[(NC + k) * NC + j];
  z[b * NC + j] = a2;
}

// ---- apply: BN finalize (decomposed stats) + out = relu((g+z[seg])*sc+sh) ----
__global__ __launch_bounds__(256) void k_apply(
    const unsigned short* __restrict__ g_bf, const int* __restrict__ o,
    const float* __restrict__ z, const float* __restrict__ hseg,
    const float* __restrict__ gsumsq, const float* __restrict__ gamma,
    const float* __restrict__ beta, float* __restrict__ out) {
  __shared__ float s_scale[NC], s_shift[NC];
  __shared__ int o_s[NSEG];
  int t = threadIdx.x;
  int row0 = blockIdx.x * 64;
  if (t < NSEG) o_s[t] = o[t];
  __syncthreads();
  {  // colsum = Σ hseg + Σ cnt·z ; colsumsq = gsumsq + Σ(2·hseg+cnt·z)·z
    float cs = 0.f, cq = gsumsq[t];
    int prev = 0;
#pragma unroll
    for (int s = 0; s < NSEG; ++s) {
      float cnt = (float)(o_s[s] - prev);
      prev = o_s[s];
      float hs = hseg[s * NC + t], zz = z[s * NC + t];
      cs += hs + cnt * zz;
      cq += (2.f * hs + cnt * zz) * zz;
    }
    float invN = 1.f / (float)N_PTS;
    float mu = cs * invN;
    float var = cq * invN - mu * mu;
    float sc = gamma[t] * rsqrtf(var + BN_EPSF);
    s_scale[t] = sc;
    s_shift[t] = beta[t] - mu * sc;
  }
  __syncthreads();
  int s0 = 0;
  while (o_s[s0] <= row0) ++s0;
  int e0 = o_s[s0];
  int s1 = (s0 < NSEG - 1) ? s0 + 1 : s0;
  int cg = (t & 31) * 8, rsub = t >> 5;
  float4 sc0 = *(const float4*)(s_scale + cg), sc1 = *(const float4*)(s_scale + cg + 4);
  float4 sh0 = *(const float4*)(s_shift + cg), sh1 = *(const float4*)(s_shift + cg + 4);
  float4 zA0 = *(const float4*)(z + s0 * NC + cg), zA1 = *(const float4*)(z + s0 * NC + cg + 4);
  float4 zB0 = *(const float4*)(z + s1 * NC + cg), zB1 = *(const float4*)(z + s1 * NC + cg + 4);
#pragma unroll
  for (int i = 0; i < 8; ++i) {
    int row = row0 + rsub + i * 8;
    uint4 hv = *(const uint4*)(g_bf + (size_t)row * NC + cg);
    bool inA = (row < e0);
    float4 z0 = inA ? zA0 : zB0;
    float4 z1 = inA ? zA1 : zB1;
    float4 o0, o1;
    o0.x = fmaxf((bf2f((unsigned short)(hv.x & 0xffffu)) + z0.x) * sc0.x + sh0.x, 0.f);
    o0.y = fmaxf((bf2f((unsigned short)(hv.x >> 16)) + z0.y) * sc0.y + sh0.y, 0.f);
    o0.z = fmaxf((bf2f((unsigned short)(hv.y & 0xffffu)) + z0.z) * sc0.z + sh0.z, 0.f);
    o0.w = fmaxf((bf2f((unsigned short)(hv.y >> 16)) + z0.w) * sc0.w + sh0.w, 0.f);
    o1.x = fmaxf((bf2f((unsigned short)(hv.z & 0xffffu)) + z1.x) * sc1.x + sh1.x, 0.f);
    o1.y = fmaxf((bf2f((unsigned short)(hv.z >> 16)) + z1.y) * sc1.y + sh1.y, 0.f);
    o1.z = fmaxf((bf2f((unsigned short)(hv.w & 0xffffu)) + z1.z) * sc1.z + sh1.z, 0.f);
    o1.w = fmaxf((bf2f((unsigned short)(hv.w >> 16)) + z1.w) * sc1.w + sh1.w, 0.f);
    *(float4*)(out + (size_t)row * NC + cg) = o0;
    *(float4*)(out + (size_t)row * NC + cg + 4) = o1;
  }
}

extern "C" void kernel_launch(void* const* d_in, const int* in_sizes, int n_in,
                              void* d_out, int out_size, void* d_ws, size_t ws_size,
                              hipStream_t stream) {
  const float* x = (const float*)d_in[0];
  const int* o = (const int*)d_in[1];
  const float* W1 = (const float*)d_in[2];
  const float* b1 = (const float*)d_in[3];
  const float* W2 = (const float*)d_in[4];
  const float* b2 = (const float*)d_in[5];
  const float* gamma = (const float*)d_in[6];
  const float* beta = (const float*)d_in[7];
  float* out = (float*)d_out;

  char* ws = (char*)d_ws;
  unsigned short* g_bf = (unsigned short*)ws;          // 64 MiB
  char* base2 = ws + 67108864;
  float* seg_sums = (float*)(base2);                   // 16 KiB (zeroed)
  float* hseg     = (float*)(base2 + 16384);           // 16 KiB (zeroed)
  float* gsumsq   = (float*)(base2 + 32768);           // 1 KiB  (zeroed)
  float* z        = (float*)(base2 + 33792);           // 16 KiB
  unsigned short* w1t = (unsigned short*)(base2 + 50176);  // 128 KiB, plain [col][k]

  k_prep<<<49, 256, 0, stream>>>(W1, w1t, seg_sums);   // zeroes seg_sums..gsumsq
  k_gemm1<<<512, 512, 0, stream>>>(x, o, w1t, g_bf, seg_sums, hseg, gsumsq);
  k_seg_mlp<<<16, 256, 0, stream>>>(o, seg_sums, W1, b1, W2, b2, z);
  k_apply<<<2048, 256, 0, stream>>>(g_bf, o, z, hseg, gsumsq, gamma, beta, out);
}